// Round 8
// baseline (140.811 us; speedup 1.0000x reference)
//
#include <hip/hip_runtime.h>
#include <math.h>

#define DIM 4096

// 256 threads/block (4 waves), TWO states per block (A,B), interleaved for
// intra-wave ILP: every latency stall in A's gate chain is covered by B's
// independent stream. Amp index i = t*16 + j:
//   j bits 3..0   = i bits 3..0   = wires 8..11 -> in-register butterflies
//   lane bits     = i bits 9..4   = wires 2..7  -> cross-lane gates
//       masks 1,2,8 -> 1 DPP op; mask 4 -> 2 DPP ops (VALU pipe)
//       masks 16,32 -> ds_swizzle / ds_bpermute (DS crossbar, select-free)
//   wave bits     = i bits 11..10 = wires 0..1  -> fused with CNOT chain
//                                   sigma(i)=i^(i>>1) into one LDS 4-partner gather
// LDS slot swizzle: S(i) = i ^ h4((i>>4)&15), h4 = inverse Gray map; both the
// linear write and the sigma-gather read are bank-conflict-free (measured 0).
// Wave-gate coefficients and gather addresses are shared by A and B.

__device__ __forceinline__ int h4(int x) {
  return (x ^ (x >> 1) ^ (x >> 2) ^ (x >> 3)) & 15;
}

// Cross-lane exchange of x with lane^M partner.
template<int M>
__device__ __forceinline__ float xch(float x, int paddr) {
  int xi = __float_as_int(x);
  if constexpr (M == 1) {        // quad_perm [1,0,3,2]
    return __int_as_float(__builtin_amdgcn_mov_dpp(xi, 0xB1, 0xF, 0xF, false));
  } else if constexpr (M == 2) { // quad_perm [2,3,0,1]
    return __int_as_float(__builtin_amdgcn_mov_dpp(xi, 0x4E, 0xF, 0xF, false));
  } else if constexpr (M == 4) {
    // banks 0,2 need src[i+4] -> row_shl:4; banks 1,3 need src[i-4] -> row_shr:4
    int r = __builtin_amdgcn_update_dpp(xi, xi, 0x104, 0xF, 0x5, false);
    r     = __builtin_amdgcn_update_dpp(r,  xi, 0x114, 0xF, 0xA, false);
    return __int_as_float(r);
  } else if constexpr (M == 8) { // row_ror:8 == xor 8 within 16-lane row
    return __int_as_float(__builtin_amdgcn_mov_dpp(xi, 0x128, 0xF, 0xF, false));
  } else if constexpr (M == 16) { // xor-16 via LDS crossbar (BitMode)
    return __int_as_float(__builtin_amdgcn_ds_swizzle(xi, 0x401F));
  } else {                       // M == 32: cross-half via bpermute
    return __int_as_float(__builtin_amdgcn_ds_bpermute(paddr, xi));
  }
}

template<int M>
__device__ __forceinline__ void lane_gate(float4 g, int t, int paddr,
                                          float* __restrict__ re,
                                          float* __restrict__ im) {
  const bool hi = (t & M) != 0;
  const float sgn = hi ? -1.f : 1.f;
  const float ar = g.x, cai = sgn * g.y, cbr = sgn * g.z, cbi = g.w;
  #pragma unroll
  for (int p = 0; p < 16; ++p) {
    float pr = xch<M>(re[p], paddr);
    float pi = xch<M>(im[p], paddr);
    float o_r = re[p], o_i = im[p];
    re[p] = ar*o_r - cai*o_i + cbr*pr - cbi*pi;
    im[p] = ar*o_i + cai*o_r + cbr*pi + cbi*pr;
  }
}

// All gates on wires 2..11 for layer L, applied to one state's registers.
__device__ __forceinline__ void reg_lane_gates(const float4* __restrict__ ga4,
                                               int L, int t, int paddr,
                                               float* __restrict__ re,
                                               float* __restrict__ im) {
  #pragma unroll
  for (int w = 8; w <= 11; ++w) {
    const int m = 1 << (11 - w);
    float4 g = ga4[L*12 + w];
    float ar = g.x, ai = g.y, br = g.z, bi = g.w;
    #pragma unroll
    for (int p = 0; p < 16; ++p) {
      if (!(p & m)) {
        const int k2 = p | m;
        float v0r = re[p], v0i = im[p], v1r = re[k2], v1i = im[k2];
        re[p]  =  ar*v0r - ai*v0i + br*v1r - bi*v1i;
        im[p]  =  ar*v0i + ai*v0r + br*v1i + bi*v1r;
        re[k2] = -br*v0r - bi*v0i + ar*v1r + ai*v1i;
        im[k2] = -br*v0i + bi*v0r + ar*v1i - ai*v1r;
      }
    }
  }
  lane_gate<32>(ga4[L*12 + 2], t, paddr, re, im);
  lane_gate<16>(ga4[L*12 + 3], t, paddr, re, im);
  lane_gate< 8>(ga4[L*12 + 4], t, paddr, re, im);
  lane_gate< 4>(ga4[L*12 + 5], t, paddr, re, im);
  lane_gate< 2>(ga4[L*12 + 6], t, paddr, re, im);
  lane_gate< 1>(ga4[L*12 + 7], t, paddr, re, im);
}

struct C8 { float c0r,c0i,c1r,c1i,c2r,c2i,c3r,c3i; };

// Fused wave gates (wires 0,1) + CNOT chain: 4-partner LDS gather.
__device__ __forceinline__ void gather8(const float2* __restrict__ st2, int gb,
                                        const C8& c,
                                        float* __restrict__ re,
                                        float* __restrict__ im) {
  #pragma unroll
  for (int j = 0; j < 16; ++j) {
    const int base = gb ^ (j ^ (j >> 1));
    float2 m0 = st2[base];
    float2 m1 = st2[base + 1024];
    float2 m2 = st2[base + 2048];
    float2 m3 = st2[base + 3072];
    re[j] = c.c0r*m0.x - c.c0i*m0.y + c.c1r*m1.x - c.c1i*m1.y
          + c.c2r*m2.x - c.c2i*m2.y + c.c3r*m3.x - c.c3i*m3.y;
    im[j] = c.c0r*m0.y + c.c0i*m0.x + c.c1r*m1.y + c.c1i*m1.x
          + c.c2r*m2.y + c.c2i*m2.x + c.c3r*m3.y + c.c3i*m3.x;
  }
}

__global__ __launch_bounds__(256)
void qsim_kernel(const float* __restrict__ in, const float* __restrict__ params,
                 const float* __restrict__ hw, const float* __restrict__ hb,
                 float* __restrict__ out) {
  __shared__ float2 stA[DIM];    // 32 KB, state A, swizzled slots
  __shared__ float2 stB[DIM];    // 32 KB, state B
  __shared__ float4 ga4[36];     // fused RZ@RY@RX: (a.re, a.im, b.re, b.im)
  __shared__ float red[8];

  const int t = threadIdx.x;
  const int b = blockIdx.x;      // states 2b and 2b+1

  // Fused gate matrices M = RZ@RY@RX = [[a,b],[-conj(b),conj(a)]]
  if (t < 36) {
    const float* P = params + t * 3;
    float hx = P[0]*0.5f, hy = P[1]*0.5f, hz = P[2]*0.5f;
    float cx = cosf(hx), sx = sinf(hx);
    float cy = cosf(hy), sy = sinf(hy);
    float cz = cosf(hz), sz = sinf(hz);
    float arr = cy*cx, aii = sy*sx, brr = sy*cx, bii = cy*sx;
    ga4[t] = make_float4(cz*arr + sz*aii,
                         cz*aii - sz*arr,
                         -(cz*brr + sz*bii),
                         -(cz*bii - sz*brr));
  }

  // ---- load 16 consecutive amps per state + block-wide norms ----
  float reA[16], imA[16], reB[16], imB[16];
  const float* inA = in + (size_t)(2*b)   * DIM + t * 16;
  const float* inB = in + (size_t)(2*b+1) * DIM + t * 16;
  float ssA = 0.f, ssB = 0.f;
  #pragma unroll
  for (int q = 0; q < 4; ++q) {
    float4 va = reinterpret_cast<const float4*>(inA)[q];
    float4 vb = reinterpret_cast<const float4*>(inB)[q];
    reA[4*q+0]=va.x; reA[4*q+1]=va.y; reA[4*q+2]=va.z; reA[4*q+3]=va.w;
    reB[4*q+0]=vb.x; reB[4*q+1]=vb.y; reB[4*q+2]=vb.z; reB[4*q+3]=vb.w;
    ssA += va.x*va.x + va.y*va.y + va.z*va.z + va.w*va.w;
    ssB += vb.x*vb.x + vb.y*vb.y + vb.z*vb.z + vb.w*vb.w;
  }
  #pragma unroll
  for (int o = 1; o < 64; o <<= 1) {
    ssA += __shfl_xor(ssA, o, 64);
    ssB += __shfl_xor(ssB, o, 64);
  }
  if ((t & 63) == 0) { red[t >> 6] = ssA; red[4 + (t >> 6)] = ssB; }
  __syncthreads();               // also publishes ga4
  float invA = 1.0f / sqrtf(red[0] + red[1] + red[2] + red[3]);
  float invB = 1.0f / sqrtf(red[4] + red[5] + red[6] + red[7]);
  #pragma unroll
  for (int j = 0; j < 16; ++j) {
    reA[j] *= invA; imA[j] = 0.f;
    reB[j] *= invB; imB[j] = 0.f;
  }

  // thread-constant addressing (all GF(2)-linear in i)
  const int wbase = (t << 4) ^ h4(t & 15);          // write slot = wbase ^ j
  const int sig   = (t << 4) ^ (t << 3);            // sigma(i) thread part
  const int sigc  = sig & 1023;                     // bits 11,10 cleared
  const int gb    = sigc ^ h4((sigc >> 4) & 15);    // gather slot = gb ^ gray(j) + y*1024
  const int x11   = (t >> 7) & 1;                   // sigma(i) bit 11 (wire 0)
  const int x10   = ((t >> 6) ^ (t >> 7)) & 1;      // sigma(i) bit 10 (wire 1)
  const int paddr = ((t ^ 32) & 63) << 2;           // bpermute addr for mask 32

  #pragma unroll 1
  for (int L = 0; L < 3; ++L) {
    // ---- gates on wires 2..11, both states (independent streams -> ILP) ----
    reg_lane_gates(ga4, L, t, paddr, reA, imA);
    reg_lane_gates(ga4, L, t, paddr, reB, imB);

    // ---- write post-gate states (conflict-free swizzled) ----
    #pragma unroll
    for (int j = 0; j < 16; ++j) {
      stA[wbase ^ j] = make_float2(reA[j], imA[j]);
      stB[wbase ^ j] = make_float2(reB[j], imB[j]);
    }
    __syncthreads();

    // ---- wave-gate coefficients (shared by A and B) ----
    float4 g0 = ga4[L*12 + 0], g1 = ga4[L*12 + 1];
    float u0r, u0i, u1r, u1i, v0r, v0i, v1r, v1i;
    if (x11) { u0r = -g0.z; u0i = g0.w; u1r = g0.x; u1i = -g0.y; }
    else     { u0r =  g0.x; u0i = g0.y; u1r = g0.z; u1i =  g0.w; }
    if (x10) { v0r = -g1.z; v0i = g1.w; v1r = g1.x; v1i = -g1.y; }
    else     { v0r =  g1.x; v0i = g1.y; v1r = g1.z; v1i =  g1.w; }
    C8 c;
    c.c0r = u0r*v0r - u0i*v0i; c.c0i = u0r*v0i + u0i*v0r;
    c.c1r = u0r*v1r - u0i*v1i; c.c1i = u0r*v1i + u0i*v1r;
    c.c2r = u1r*v0r - u1i*v0i; c.c2i = u1r*v0i + u1i*v0r;
    c.c3r = u1r*v1r - u1i*v1i; c.c3i = u1r*v1i + u1i*v1r;

    // ---- fused wave gates + CNOT gather, both states ----
    gather8(stA, gb, c, reA, imA);
    gather8(stB, gb, c, reB, imB);
    if (L != 2) __syncthreads();  // WAR guard; not needed after last gather
  }

  // ---- readout: sum |amp|^2 * c(i) for both states ----
  float Ct = 0.f;
  #pragma unroll
  for (int p = 0; p < 8; ++p) Ct += hw[7-p] * (((t >> p) & 1) ? -1.f : 1.f);
  float h11 = hw[11], h10 = hw[10], h9 = hw[9], h8 = hw[8];
  float accA = 0.f, accB = 0.f;
  #pragma unroll
  for (int j = 0; j < 16; ++j) {
    float cj = Ct + ((j&1) ? -h11 : h11) + ((j&2) ? -h10 : h10)
             + ((j&4) ? -h9  : h9 ) + ((j&8) ? -h8  : h8 );
    accA += (reA[j]*reA[j] + imA[j]*imA[j]) * cj;
    accB += (reB[j]*reB[j] + imB[j]*imB[j]) * cj;
  }
  #pragma unroll
  for (int o = 1; o < 64; o <<= 1) {
    accA += __shfl_xor(accA, o, 64);
    accB += __shfl_xor(accB, o, 64);
  }
  __syncthreads();  // red[] free (norm phase long done on all waves)
  if ((t & 63) == 0) { red[t >> 6] = accA; red[4 + (t >> 6)] = accB; }
  __syncthreads();
  if (t == 0) {
    out[2*b]   = red[0] + red[1] + red[2] + red[3] + hb[0];
    out[2*b+1] = red[4] + red[5] + red[6] + red[7] + hb[0];
  }
}

extern "C" void kernel_launch(void* const* d_in, const int* in_sizes, int n_in,
                              void* d_out, int out_size, void* d_ws, size_t ws_size,
                              hipStream_t stream) {
  const float* st     = (const float*)d_in[0];
  const float* params = (const float*)d_in[1];
  const float* hwp    = (const float*)d_in[2];
  const float* hbp    = (const float*)d_in[3];
  float* outp = (float*)d_out;
  int batch = in_sizes[0] / DIM;
  qsim_kernel<<<batch / 2, 256, 0, stream>>>(st, params, hwp, hbp, outp);
}

// Round 9
// 64.140 us; speedup vs baseline: 2.1954x; 2.1954x over previous
//
#include <hip/hip_runtime.h>
#include <math.h>

#define DIM 4096

// 256 threads/block (4 waves), one block per state — R7 structure (proven
// 115 us, absmax 3e-5) with the complex math rewritten in packed FP32:
// state amp = (re,im) in one VGPR pair; every complex MAC = 2x v_pk_fma_f32
// with op_sel/neg folding the swap/conjugate/negate (2 FLOP/lane/instr —
// the only path to the 157 TF fp32 vector peak; scalar v_fma = 103 TF).
//   j bits 3..0   = wires 8..11 -> in-register butterflies (packed)
//   lane bits     = wires 2..7  -> cross-lane gates:
//       masks 1,2,8 -> 1 DPP op; mask 4 -> 2 DPP ops (VALU)
//       masks 16,32 -> ds_swizzle / ds_bpermute (DS crossbar, select-free)
//   wave bits     = wires 0..1  -> fused with CNOT chain sigma(i)=i^(i>>1)
//                                  into one LDS 4-partner gather (packed)
// LDS slot swizzle S(i) = i ^ h4((i>>4)&15), h4 = inverse Gray map; write and
// sigma-gather are both bank-conflict-free (measured 0).

typedef float f2 __attribute__((ext_vector_type(2)));

// ---- packed complex primitives (VOP3P op_sel semantics:
// op_sel[k] picks src-k half feeding the LOW result, op_sel_hi[k] the HIGH;
// neg_lo/neg_hi negate that source for that half) ----

// acc += c*v : lo += cr*vr - ci*vi ; hi += cr*vi + ci*vr
__device__ __forceinline__ f2 cfma(f2 acc, f2 c, f2 v) {
  asm("v_pk_fma_f32 %0, %1, %2, %0 op_sel:[0,0,0] op_sel_hi:[0,1,1]\n\t"
      "v_pk_fma_f32 %0, %1, %2, %0 op_sel:[1,1,0] op_sel_hi:[1,0,1] neg_lo:[1,0,0]"
      : "+&v"(acc) : "v"(c), "v"(v));
  return acc;
}
// acc += conj(c)*v : lo += cr*vr + ci*vi ; hi += cr*vi - ci*vr
__device__ __forceinline__ f2 cfma_cj(f2 acc, f2 c, f2 v) {
  asm("v_pk_fma_f32 %0, %1, %2, %0 op_sel:[0,0,0] op_sel_hi:[0,1,1]\n\t"
      "v_pk_fma_f32 %0, %1, %2, %0 op_sel:[1,1,0] op_sel_hi:[1,0,1] neg_hi:[1,0,0]"
      : "+&v"(acc) : "v"(c), "v"(v));
  return acc;
}
// d = c*v
__device__ __forceinline__ f2 cmul(f2 c, f2 v) {
  f2 d;
  asm("v_pk_mul_f32 %0, %1, %2 op_sel:[0,0] op_sel_hi:[0,1]\n\t"
      "v_pk_fma_f32 %0, %1, %2, %0 op_sel:[1,1,0] op_sel_hi:[1,0,1] neg_lo:[1,0,0]"
      : "=&v"(d) : "v"(c), "v"(v));
  return d;
}
// d = -conj(c)*v : lo = -cr*vr - ci*vi ; hi = -cr*vi + ci*vr
__device__ __forceinline__ f2 cmul_ncj(f2 c, f2 v) {
  f2 d;
  asm("v_pk_mul_f32 %0, %1, %2 op_sel:[0,0] op_sel_hi:[0,1] neg_lo:[1,0] neg_hi:[1,0]\n\t"
      "v_pk_fma_f32 %0, %1, %2, %0 op_sel:[1,1,0] op_sel_hi:[1,0,1] neg_lo:[1,0,0]"
      : "=&v"(d) : "v"(c), "v"(v));
  return d;
}

__device__ __forceinline__ int h4(int x) {
  return (x ^ (x >> 1) ^ (x >> 2) ^ (x >> 3)) & 15;
}

// Cross-lane exchange of x with lane^M partner.
template<int M>
__device__ __forceinline__ float xch(float x, int paddr) {
  int xi = __float_as_int(x);
  if constexpr (M == 1) {        // quad_perm [1,0,3,2]
    return __int_as_float(__builtin_amdgcn_mov_dpp(xi, 0xB1, 0xF, 0xF, false));
  } else if constexpr (M == 2) { // quad_perm [2,3,0,1]
    return __int_as_float(__builtin_amdgcn_mov_dpp(xi, 0x4E, 0xF, 0xF, false));
  } else if constexpr (M == 4) {
    // banks 0,2 need src[i+4] -> row_shl:4; banks 1,3 need src[i-4] -> row_shr:4
    int r = __builtin_amdgcn_update_dpp(xi, xi, 0x104, 0xF, 0x5, false);
    r     = __builtin_amdgcn_update_dpp(r,  xi, 0x114, 0xF, 0xA, false);
    return __int_as_float(r);
  } else if constexpr (M == 8) { // row_ror:8 == xor 8 within 16-lane row
    return __int_as_float(__builtin_amdgcn_mov_dpp(xi, 0x128, 0xF, 0xF, false));
  } else if constexpr (M == 16) { // xor-16 via LDS crossbar (BitMode)
    return __int_as_float(__builtin_amdgcn_ds_swizzle(xi, 0x401F));
  } else {                       // M == 32: cross-half via bpermute
    return __int_as_float(__builtin_amdgcn_ds_bpermute(paddr, xi));
  }
}

template<int M>
__device__ __forceinline__ void lane_gate(float4 g, int t, int paddr,
                                          f2* __restrict__ z) {
  const bool hi = (t & M) != 0;
  const float sgn = hi ? -1.f : 1.f;
  const f2 c1 = { g.x, sgn * g.y };   // ar + i*cai
  const f2 c2 = { sgn * g.z, g.w };   // cbr + i*cbi
  #pragma unroll
  for (int p = 0; p < 16; ++p) {
    f2 pp;
    pp.x = xch<M>(z[p].x, paddr);
    pp.y = xch<M>(z[p].y, paddr);
    z[p] = cfma(cmul(c1, z[p]), c2, pp);
  }
}

__global__ __launch_bounds__(256)
void qsim_kernel(const float* __restrict__ in, const float* __restrict__ params,
                 const float* __restrict__ hw, const float* __restrict__ hb,
                 float* __restrict__ out) {
  __shared__ f2 st2[DIM];        // 32 KB: (re, im) per amplitude, swizzled slots
  __shared__ float4 ga4[36];     // fused RZ@RY@RX: (a.re, a.im, b.re, b.im)
  __shared__ float red[4];

  const int t = threadIdx.x;
  const int b = blockIdx.x;

  // Fused gate matrices M = RZ@RY@RX = [[a,b],[-conj(b),conj(a)]]
  if (t < 36) {
    const float* P = params + t * 3;
    float hx = P[0]*0.5f, hy = P[1]*0.5f, hz = P[2]*0.5f;
    float cx = cosf(hx), sx = sinf(hx);
    float cy = cosf(hy), sy = sinf(hy);
    float cz = cosf(hz), sz = sinf(hz);
    float arr = cy*cx, aii = sy*sx, brr = sy*cx, bii = cy*sx;
    ga4[t] = make_float4(cz*arr + sz*aii,
                         cz*aii - sz*arr,
                         -(cz*brr + sz*bii),
                         -(cz*bii - sz*brr));
  }

  // ---- load 16 consecutive amps + block-wide norm ----
  float ld[16];
  const float* inb = in + (size_t)b * DIM + t * 16;
  float ss = 0.f;
  #pragma unroll
  for (int q = 0; q < 4; ++q) {
    float4 v = reinterpret_cast<const float4*>(inb)[q];
    ld[4*q+0]=v.x; ld[4*q+1]=v.y; ld[4*q+2]=v.z; ld[4*q+3]=v.w;
    ss += v.x*v.x + v.y*v.y + v.z*v.z + v.w*v.w;
  }
  #pragma unroll
  for (int o = 1; o < 64; o <<= 1) ss += __shfl_xor(ss, o, 64);
  if ((t & 63) == 0) red[t >> 6] = ss;
  __syncthreads();               // also publishes ga4
  float inv = 1.0f / sqrtf(red[0] + red[1] + red[2] + red[3]);
  f2 z[16];
  #pragma unroll
  for (int j = 0; j < 16; ++j) z[j] = (f2){ ld[j] * inv, 0.f };

  // thread-constant addressing (all GF(2)-linear in i)
  const int wbase = (t << 4) ^ h4(t & 15);          // write slot = wbase ^ j
  const int sig   = (t << 4) ^ (t << 3);            // sigma(i) thread part
  const int sigc  = sig & 1023;                     // bits 11,10 cleared
  const int gb    = sigc ^ h4((sigc >> 4) & 15);    // gather slot = gb ^ gray(j) + y*1024
  const int x11   = (t >> 7) & 1;                   // sigma(i) bit 11 (wire 0)
  const int x10   = ((t >> 6) ^ (t >> 7)) & 1;      // sigma(i) bit 10 (wire 1)
  const int paddr = ((t ^ 32) & 63) << 2;           // bpermute addr for mask 32

  #pragma unroll 1
  for (int L = 0; L < 3; ++L) {
    // ---- 4 register gates: wires 8..11, mask on j (packed butterflies) ----
    #pragma unroll
    for (int w = 8; w <= 11; ++w) {
      const int m = 1 << (11 - w);
      float4 g = ga4[L*12 + w];
      const f2 a  = { g.x, g.y };
      const f2 bb = { g.z, g.w };
      #pragma unroll
      for (int p = 0; p < 16; ++p) {
        if (!(p & m)) {
          const int k2 = p | m;
          f2 v0 = z[p], v1 = z[k2];
          z[p]  = cfma(cmul(a, v0), bb, v1);        // a*v0 + b*v1
          z[k2] = cfma_cj(cmul_ncj(bb, v0), a, v1); // -conj(b)*v0 + conj(a)*v1
        }
      }
    }
    // ---- 6 lane gates: wires 2..7 -> masks 32,16,8,4,2,1 ----
    lane_gate<32>(ga4[L*12 + 2], t, paddr, z);
    lane_gate<16>(ga4[L*12 + 3], t, paddr, z);
    lane_gate< 8>(ga4[L*12 + 4], t, paddr, z);
    lane_gate< 4>(ga4[L*12 + 5], t, paddr, z);
    lane_gate< 2>(ga4[L*12 + 6], t, paddr, z);
    lane_gate< 1>(ga4[L*12 + 7], t, paddr, z);

    // ---- write post-(wires 2..11) state (conflict-free swizzled) ----
    #pragma unroll
    for (int j = 0; j < 16; ++j) st2[wbase ^ j] = z[j];
    __syncthreads();

    // ---- fused: wave gates (wires 0,1) + CNOT chain, 4-partner gather ----
    // new[i] = sum_y G0[x11][y>>1]*G1[x10][y&1] * mid[sigma(i) w/ bits11,10 := y]
    float4 g0 = ga4[L*12 + 0], g1 = ga4[L*12 + 1];
    float u0r, u0i, u1r, u1i, v0r, v0i, v1r, v1i;
    if (x11) { u0r = -g0.z; u0i = g0.w; u1r = g0.x; u1i = -g0.y; }
    else     { u0r =  g0.x; u0i = g0.y; u1r = g0.z; u1i =  g0.w; }
    if (x10) { v0r = -g1.z; v0i = g1.w; v1r = g1.x; v1i = -g1.y; }
    else     { v0r =  g1.x; v0i = g1.y; v1r = g1.z; v1i =  g1.w; }
    const f2 c0 = { u0r*v0r - u0i*v0i, u0r*v0i + u0i*v0r };
    const f2 c1 = { u0r*v1r - u0i*v1i, u0r*v1i + u0i*v1r };
    const f2 c2 = { u1r*v0r - u1i*v0i, u1r*v0i + u1i*v0r };
    const f2 c3 = { u1r*v1r - u1i*v1i, u1r*v1i + u1i*v1r };
    #pragma unroll
    for (int j = 0; j < 16; ++j) {
      const int base = gb ^ (j ^ (j >> 1));
      f2 m0 = st2[base];
      f2 m1 = st2[base + 1024];
      f2 m2 = st2[base + 2048];
      f2 m3 = st2[base + 3072];
      z[j] = cfma(cfma(cfma(cmul(c0, m0), c1, m1), c2, m2), c3, m3);
    }
    if (L != 2) __syncthreads();  // WAR guard; not needed after last gather
  }

  // ---- readout: sum |amp|^2 * c(i), i = t*16 + j (regs hold final state) ----
  float Ct = 0.f;
  #pragma unroll
  for (int p = 0; p < 8; ++p) Ct += hw[7-p] * (((t >> p) & 1) ? -1.f : 1.f);
  float h11 = hw[11], h10 = hw[10], h9 = hw[9], h8 = hw[8];
  float acc = 0.f;
  #pragma unroll
  for (int j = 0; j < 16; ++j) {
    float pj = z[j].x*z[j].x + z[j].y*z[j].y;
    float cj = Ct + ((j&1) ? -h11 : h11) + ((j&2) ? -h10 : h10)
             + ((j&4) ? -h9  : h9 ) + ((j&8) ? -h8  : h8 );
    acc += pj * cj;
  }
  #pragma unroll
  for (int o = 1; o < 64; o <<= 1) acc += __shfl_xor(acc, o, 64);
  if ((t & 63) == 0) red[t >> 6] = acc;
  __syncthreads();
  if (t == 0) out[b] = red[0] + red[1] + red[2] + red[3] + hb[0];
}

extern "C" void kernel_launch(void* const* d_in, const int* in_sizes, int n_in,
                              void* d_out, int out_size, void* d_ws, size_t ws_size,
                              hipStream_t stream) {
  const float* st     = (const float*)d_in[0];
  const float* params = (const float*)d_in[1];
  const float* hwp    = (const float*)d_in[2];
  const float* hbp    = (const float*)d_in[3];
  float* outp = (float*)d_out;
  int batch = in_sizes[0] / DIM;
  qsim_kernel<<<batch, 256, 0, stream>>>(st, params, hwp, hbp, outp);
}